// Round 13
// baseline (458.109 us; speedup 1.0000x reference)
//
#include <hip/hip_runtime.h>
#include <math.h>

// Problem constants (from reference setup_inputs)
constexpr int NV  = 16000;   // voxels
constexpr int P   = 32;      // points per voxel
constexpr int CIN = 10;      // input channels
constexpr int CV  = 64;      // voxel feature channels
constexpr int NB  = 16000;   // BEV cells
constexpr int BEV_H = 496, BEV_W = 432;
constexpr int HW = BEV_H * BEV_W;  // 214272
constexpr float EPS = 1e-5f;

typedef __attribute__((ext_vector_type(8))) short short8_t;  // 8 bf16 (4 VGPR)
typedef __attribute__((ext_vector_type(4))) short short4_t;  // 4 bf16
typedef __attribute__((ext_vector_type(4))) float fx4;       // MFMA C/D frag
typedef __attribute__((ext_vector_type(2))) float f32x2;     // packed f32 pair

// 8-op mish: tanh(softplus(x)) = 1 - 2/((1+e^x)^2+1)  ->  mish = x - 2x/d
__device__ __forceinline__ float mish(float x) {
  float e = __expf(fminf(x, 15.f));
  float u = 1.f + e;
  float d = fmaf(u, u, 1.f);
  float r = __builtin_amdgcn_rcpf(d);
  return fmaf(-2.f * x, r, x);
}

// packed-pair mish: v_pk_* for the mul/add/fma lattice, scalar exp/rcp.
// Bit-identical to scalar mish applied per element.
__device__ __forceinline__ f32x2 mish2(f32x2 x) {
  f32x2 xc = __builtin_elementwise_min(x, (f32x2){15.f, 15.f});
  f32x2 e  = { __expf(xc[0]), __expf(xc[1]) };
  f32x2 u  = e + (f32x2){1.f, 1.f};
  f32x2 d  = __builtin_elementwise_fma(u, u, (f32x2){1.f, 1.f});
  f32x2 r  = { __builtin_amdgcn_rcpf(d[0]), __builtin_amdgcn_rcpf(d[1]) };
  f32x2 m2x = x * (f32x2){-2.f, -2.f};
  return __builtin_elementwise_fma(m2x, r, x);
}
// packed LN apply: (a*rstd + ms)*g + b  (two v_pk_fma)
__device__ __forceinline__ f32x2 ln2(f32x2 a, f32x2 rs, f32x2 msv, f32x2 go, f32x2 bo) {
  return __builtin_elementwise_fma(__builtin_elementwise_fma(a, rs, msv), go, bo);
}

// RNE f32->bf16 (cold paths: weight packing)
__device__ __forceinline__ short f2bf(float f) {
  unsigned u = __builtin_bit_cast(unsigned, f);
  u += 0x7FFF + ((u >> 16) & 1);
  return (short)(u >> 16);
}
__device__ __forceinline__ float bf2f(short s) {
  unsigned u = ((unsigned)(unsigned short)s) << 16;
  return __builtin_bit_cast(float, u);
}
__device__ __forceinline__ short8_t pack8(const float* t) {
  short8_t s;
#pragma unroll
  for (int j = 0; j < 8; ++j) s[j] = f2bf(t[j]);
  return s;
}

// hot-path pack: round-half-up + v_perm pair  (low16 = bf16(a), high16 = bf16(b))
__device__ __forceinline__ unsigned bfpair(float a, float b) {
  unsigned au = __builtin_bit_cast(unsigned, a) + 0x8000u;
  unsigned bu = __builtin_bit_cast(unsigned, b) + 0x8000u;
  return __builtin_amdgcn_perm(bu, au, 0x07060302u);
}
// Dekker-style split pair: returns hi-pack, writes exact lo residuals
__device__ __forceinline__ unsigned hipack(float a, float b, float& la, float& lb) {
  unsigned ua = (__builtin_bit_cast(unsigned, a) + 0x8000u) & 0xFFFF0000u;
  unsigned ub = (__builtin_bit_cast(unsigned, b) + 0x8000u) & 0xFFFF0000u;
  la = a - __builtin_bit_cast(float, ua);
  lb = b - __builtin_bit_cast(float, ub);
  return __builtin_amdgcn_perm(ub, ua, 0x07060302u);
}

// ---------------------------------------------------------------------------
// Fused VFE + weight-pack kernel (unchanged from R11/R12 passing config).
// ---------------------------------------------------------------------------
constexpr int VFE_BLOCKS  = NV / 16;   // 1000
constexpr int PACK_BLOCKS = 208;       // 208*512 = 106496

__global__ __launch_bounds__(512, 4) void vfe_pack_kernel(
    const float* __restrict__ voxels, const float* __restrict__ vmask,
    const float* __restrict__ W1, const float* __restrict__ g1, const float* __restrict__ b1,
    const float* __restrict__ W2, const float* __restrict__ g2, const float* __restrict__ b2,
    const float* __restrict__ W3, const float* __restrict__ g3, const float* __restrict__ b3,
    const float* __restrict__ W4, const float* __restrict__ g4, const float* __restrict__ b4,
    unsigned short* __restrict__ voxelwise,
    const float* __restrict__ bW1, const float* __restrict__ bW2a,
    const float* __restrict__ bW2b, const float* __restrict__ bW3,
    const int* __restrict__ bevcoors,
    short* __restrict__ w1h, short* __restrict__ w2ah, short* __restrict__ w2bh,
    short* __restrict__ w3h, short* __restrict__ w3l,
    int* __restrict__ invmap)
{
  __shared__ short wlds[28 * 512];                 // 28672 B
  __shared__ short actb[8][16 * 72];               // 18432 B (wave-private act buf)
  __shared__ float gblds[512];                     //  2048 B
  __shared__ unsigned short pairbuf[2][4][4][64];  //  4096 B bf16

  const int tid = threadIdx.x;

  // ---------------- pack path (blocks >= VFE_BLOCKS) ----------------
  if (blockIdx.x >= VFE_BLOCKS) {
    int i = (blockIdx.x - VFE_BLOCKS) * 512 + tid;
    if (i < NB) {
      int2 hw2 = *(const int2*)&bevcoors[i * 2];   // (h, w)
      invmap[hw2.y * BEV_H + hw2.x] = i;
    }
    if (i < 65536) {
      w1h[i] = f2bf(bW1[i]);
    } else if (i < 81920) {
      int j = i - 65536;
      int g = j >> 10, o = (j >> 6) & 15, c = j & 63;
      float v = (o < 8) ? bW2a[(g * 8 + o) * 64 + c] : 0.f;
      w2ah[j] = f2bf(v);
    } else if (i < 90112) {
      int k = i - 81920;
      int g = k >> 9, o = (k >> 5) & 15, c = k & 31;
      float v = (o < 8) ? bW2b[(g * 8 + o) * 32 + c] : 0.f;
      w2bh[k] = f2bf(v);
    } else if (i < 106496) {
      int j = i - 90112;
      float v = bW3[j];
      short h = f2bf(v);
      w3h[j] = h; w3l[j] = f2bf(v - bf2f(h));
    }
    return;
  }

  // ---------------- VFE path ----------------
  const int lane = tid & 63;
  const int w    = tid >> 6;      // 0..7
  const int pair = w >> 1;        // 0..3 (voxel group within block)
  const int h    = w & 1;         // which half of the 32 points
  const int p    = lane & 15;
  const int q    = lane >> 4;
  const int gw   = blockIdx.x * 4 + pair;

  {
    int region = tid >> 6, off = tid & 63;
    const float* src =
        region == 0 ? g1 : region == 1 ? b1 :
        region == 2 ? g2 : region == 3 ? b2 :
        region == 4 ? g3 : region == 5 ? b3 :
        region == 6 ? g4 : b4;
    gblds[tid] = src[off];
  }
  for (int s = w; s < 28; s += 8) {
    float t[8];
    if (s < 4) {
      const int f = s;
#pragma unroll
      for (int j = 0; j < 8; ++j) {
        int c = 8 * q + j;
        t[j] = (c < CIN) ? W1[(p + 16 * f) * CIN + c] : 0.f;
      }
    } else {
      const int l = (s - 4) >> 3, rem = (s - 4) & 7, ch = rem >> 2, f = rem & 3;
      const float* Wl = (l == 0) ? W2 : (l == 1) ? W3 : W4;
      const float* src = Wl + (p + 16 * f) * CV + 32 * ch + 8 * q;
#pragma unroll
      for (int j = 0; j < 8; ++j) t[j] = src[j];
    }
    *(short8_t*)&wlds[s * 512 + lane * 8] = pack8(t);
  }
  __syncthreads();

  short* mybuf = &actb[w][0];
  const fx4 zacc = {0.f, 0.f, 0.f, 0.f};
  const int srcLane = ((lane >> 2) & 3) * 16 + (((lane >> 4) & 3) << 2) + (lane & 3);

  for (int i = 0; i < 4; ++i) {
    const int v = gw * 4 + i;
    const int ptbase = v * 32 + h * 16;
    const float m = vmask[ptbase + p];
    const f32x2 mv = {m, m};
    f32x2 x2r2[8];
    float cur[16];

    // ---- layer 1 ----
    {
      const float* xrow = voxels + (size_t)(ptbase + p) * CIN;
      float t[8] = {0.f, 0.f, 0.f, 0.f, 0.f, 0.f, 0.f, 0.f};
      if (q == 0) {
        float2 a = *(const float2*)(xrow + 0);
        float2 b = *(const float2*)(xrow + 2);
        float2 c = *(const float2*)(xrow + 4);
        float2 d = *(const float2*)(xrow + 6);
        t[0] = a.x; t[1] = a.y; t[2] = b.x; t[3] = b.y;
        t[4] = c.x; t[5] = c.y; t[6] = d.x; t[7] = d.y;
      } else if (q == 1) {
        float2 a = *(const float2*)(xrow + 8);
        t[0] = a.x; t[1] = a.y;
      }
      uint4 bu = make_uint4(bfpair(t[0], t[1]), bfpair(t[2], t[3]),
                            bfpair(t[4], t[5]), bfpair(t[6], t[7]));
      short8_t bfrag = __builtin_bit_cast(short8_t, bu);
      fx4 acc[4];
#pragma unroll
      for (int f = 0; f < 4; ++f) {
        short8_t af = *(short8_t*)&wlds[f * 512 + lane * 8];
        acc[f] = __builtin_amdgcn_mfma_f32_16x16x32_bf16(af, bfrag, zacc, 0, 0, 0);
      }
      f32x2 s1v = {0.f, 0.f}, s2v = {0.f, 0.f};
#pragma unroll
      for (int f = 0; f < 4; ++f) {
        f32x2 a01 = __builtin_shufflevector(acc[f], acc[f], 0, 1);
        f32x2 a23 = __builtin_shufflevector(acc[f], acc[f], 2, 3);
        s1v = s1v + a01 + a23;
        s2v = __builtin_elementwise_fma(a01, a01, s2v);
        s2v = __builtin_elementwise_fma(a23, a23, s2v);
      }
      float s1 = s1v[0] + s1v[1], s2 = s2v[0] + s2v[1];
      s1 += __shfl_xor(s1, 16); s1 += __shfl_xor(s1, 32);
      s2 += __shfl_xor(s2, 16); s2 += __shfl_xor(s2, 32);
      float mean = s1 * (1.f / 64.f);
      float rstd = rsqrtf(fmaf(-mean, mean, s2 * (1.f / 64.f)) + EPS);
      float ms = -mean * rstd;
      const f32x2 rs = {rstd, rstd}, msv = {ms, ms};
#pragma unroll
      for (int f = 0; f < 4; ++f) {
        float4 gv = *(const float4*)&gblds[16 * f + 4 * q];
        float4 bv = *(const float4*)&gblds[64 + 16 * f + 4 * q];
        f32x2 a01 = __builtin_shufflevector(acc[f], acc[f], 0, 1);
        f32x2 a23 = __builtin_shufflevector(acc[f], acc[f], 2, 3);
        f32x2 o01 = mish2(ln2(a01, rs, msv, (f32x2){gv.x, gv.y}, (f32x2){bv.x, bv.y}));
        f32x2 o23 = mish2(ln2(a23, rs, msv, (f32x2){gv.z, gv.w}, (f32x2){bv.z, bv.w}));
        *(uint2*)&mybuf[p * 72 + 4 * q + 16 * f] =
            make_uint2(bfpair(o01[0], o01[1]), bfpair(o23[0], o23[1]));
      }
    }

    // ---- layers 2..4 ----
#pragma unroll 1
    for (int l = 0; l < 3; ++l) {
      short8_t bf0 = *(short8_t*)&mybuf[p * 72 + 8 * q];
      short8_t bf1 = *(short8_t*)&mybuf[p * 72 + 8 * q + 32];
      fx4 acc[4];
#pragma unroll
      for (int f = 0; f < 4; ++f) {
        short8_t a0 = *(short8_t*)&wlds[(4 + l * 8 + f) * 512 + lane * 8];
        short8_t a1 = *(short8_t*)&wlds[(4 + l * 8 + 4 + f) * 512 + lane * 8];
        fx4 a = __builtin_amdgcn_mfma_f32_16x16x32_bf16(a0, bf0, zacc, 0, 0, 0);
        acc[f] = __builtin_amdgcn_mfma_f32_16x16x32_bf16(a1, bf1, a, 0, 0, 0);
      }
      f32x2 s1v = {0.f, 0.f}, s2v = {0.f, 0.f};
#pragma unroll
      for (int f = 0; f < 4; ++f) {
        f32x2 a01 = __builtin_shufflevector(acc[f], acc[f], 0, 1);
        f32x2 a23 = __builtin_shufflevector(acc[f], acc[f], 2, 3);
        s1v = s1v + a01 + a23;
        s2v = __builtin_elementwise_fma(a01, a01, s2v);
        s2v = __builtin_elementwise_fma(a23, a23, s2v);
      }
      float s1 = s1v[0] + s1v[1], s2 = s2v[0] + s2v[1];
      s1 += __shfl_xor(s1, 16); s1 += __shfl_xor(s1, 32);
      s2 += __shfl_xor(s2, 16); s2 += __shfl_xor(s2, 32);
      float mean = s1 * (1.f / 64.f);
      float rstd = rsqrtf(fmaf(-mean, mean, s2 * (1.f / 64.f)) + EPS);
      float ms = -mean * rstd;
      const f32x2 rs = {rstd, rstd}, msv = {ms, ms};
      const int gbbase = (l + 1) * 128;
#pragma unroll
      for (int f = 0; f < 4; ++f) {
        float4 gv = *(const float4*)&gblds[gbbase + 16 * f + 4 * q];
        float4 bv = *(const float4*)&gblds[gbbase + 64 + 16 * f + 4 * q];
        f32x2 go01 = {gv.x, gv.y}, go23 = {gv.z, gv.w};
        f32x2 bo01 = {bv.x, bv.y}, bo23 = {bv.z, bv.w};
        f32x2 a01 = __builtin_shufflevector(acc[f], acc[f], 0, 1);
        f32x2 a23 = __builtin_shufflevector(acc[f], acc[f], 2, 3);
        if (l == 0) {
          f32x2 o01 = mish2(ln2(a01, rs, msv, go01, bo01)) * mv;
          f32x2 o23 = mish2(ln2(a23, rs, msv, go23, bo23)) * mv;
          x2r2[2 * f] = o01; x2r2[2 * f + 1] = o23;
          *(uint2*)&mybuf[p * 72 + 4 * q + 16 * f] =
              make_uint2(bfpair(o01[0], o01[1]), bfpair(o23[0], o23[1]));
        } else if (l == 1) {
          f32x2 o01 = mish2(ln2(a01, rs, msv, go01, bo01));
          f32x2 o23 = mish2(ln2(a23, rs, msv, go23, bo23));
          *(uint2*)&mybuf[p * 72 + 4 * q + 16 * f] =
              make_uint2(bfpair(o01[0], o01[1]), bfpair(o23[0], o23[1]));
        } else {
          f32x2 c01 = __builtin_elementwise_fma(
              mish2(ln2(a01, rs, msv, go01, bo01)), mv, x2r2[2 * f]);
          f32x2 c23 = __builtin_elementwise_fma(
              mish2(ln2(a23, rs, msv, go23, bo23)), mv, x2r2[2 * f + 1]);
          cur[f * 4 + 0] = c01[0]; cur[f * 4 + 1] = c01[1];
          cur[f * 4 + 2] = c23[0]; cur[f * 4 + 3] = c23[1];
        }
      }
    }

    // ---- reduce-scatter max over 16 points; lane p keeps value j=p ----
#pragma unroll
    for (int t = 0; t < 8; ++t) {
      float send = (lane & 8) ? cur[t] : cur[t + 8];
      float got  = __shfl_xor(send, 8);
      float mine = (lane & 8) ? cur[t + 8] : cur[t];
      cur[t] = fmaxf(mine, got);
    }
#pragma unroll
    for (int t = 0; t < 4; ++t) {
      float send = (lane & 4) ? cur[t] : cur[t + 4];
      float got  = __shfl_xor(send, 4);
      float mine = (lane & 4) ? cur[t + 4] : cur[t];
      cur[t] = fmaxf(mine, got);
    }
#pragma unroll
    for (int t = 0; t < 2; ++t) {
      float send = (lane & 2) ? cur[t] : cur[t + 2];
      float got  = __shfl_xor(send, 2);
      float mine = (lane & 2) ? cur[t + 2] : cur[t];
      cur[t] = fmaxf(mine, got);
    }
    {
      float send = (lane & 1) ? cur[0] : cur[1];
      float got  = __shfl_xor(send, 1);
      float mine = (lane & 1) ? cur[1] : cur[0];
      cur[0] = fmaxf(mine, got);
    }
    float hm = __shfl(cur[0], srcLane);
    // round to bf16 BEFORE the cross-half max (monotonic: identical result)
    unsigned hu = __builtin_bit_cast(unsigned, hm) + 0x8000u;
    pairbuf[h][pair][i][lane] = (unsigned short)(hu >> 16);
  }

  __syncthreads();   // all half-max vectors staged

  if (h == 0) {
#pragma unroll
    for (int i = 0; i < 4; ++i) {
      const int v = gw * 4 + i;
      float a = bf2f((short)pairbuf[0][pair][i][lane]);
      float b = bf2f((short)pairbuf[1][pair][i][lane]);
      float vmaxv = fmaxf(a, b);   // both already bf16; max is exact
      voxelwise[v * 64 + lane] =
          (unsigned short)(__builtin_bit_cast(unsigned, vmaxv) >> 16);
    }
  }
}

// ---------------------------------------------------------------------------
// Kernel 2 v12: DUAL-CHAIN INTERLEAVE. The two j-chains (g = w and g = 8+w)
// are independent except for the shared acth/h2h LDS scratch. Give j=1 its
// own scratch by REUSING the gather-panel region (dead after the layer-1
// panel reads; one extra barrier makes the reuse race-free), then process
// both chains phase-by-phase so every serial latency point has 2 independent
// ops in flight. LDS total unchanged (63680 B, 2 blocks/CU). Per-value FP op
// sequences identical -> bit-identical numerics.
// ---------------------------------------------------------------------------
constexpr int XS_CELL = 64 * 64 + 16;   // 4112 shorts: swizzled panel + 32B bank stagger
constexpr int ACT_OFF = 4 * XS_CELL;    // 16448
constexpr int ACT_WS  = 16 * 72;        // 1152 shorts per wave scratch
constexpr int GB_OFF  = ACT_OFF + 8 * ACT_WS;   // 25664 shorts (51328 B)
constexpr int GB_FLOATS = 2560;                 // g1,b1 (1024 ea) + g2a,b2a,g2b,b2b (128 ea)
constexpr int SMEM_SHORTS = GB_OFF + 2 * (GB_FLOATS + 4 * 132);  // 31840 shorts = 63680 B

__device__ __forceinline__ uint2 gather_transpose(uint2 u2, int bit0, int bit1) {
  float a0 = __builtin_bit_cast(float, u2.x << 16);
  float a1 = __builtin_bit_cast(float, u2.x & 0xFFFF0000u);
  float a2 = __builtin_bit_cast(float, u2.y << 16);
  float a3 = __builtin_bit_cast(float, u2.y & 0xFFFF0000u);
  float gv0 = bit0 ? a0 : a1, gv1 = bit0 ? a2 : a3;
  float r0 = __shfl_xor(gv0, 4), r1 = __shfl_xor(gv1, 4);
  float c0 = bit0 ? r0 : a0, c1 = bit0 ? a1 : r0;
  float c2 = bit0 ? r1 : a2, c3 = bit0 ? a3 : r1;
  float h0 = bit1 ? c0 : c2, h1 = bit1 ? c1 : c3;
  float s0 = __shfl_xor(h0, 8), s1 = __shfl_xor(h1, 8);
  float d0 = bit1 ? s0 : c0, d1 = bit1 ? s1 : c1;
  float d2 = bit1 ? c2 : s0, d3 = bit1 ? c3 : s1;
  // bfpair exact here (inputs already bf16 bit patterns)
  return make_uint2(bfpair(d0, d1), bfpair(d2, d3));
}

__global__ __launch_bounds__(512, 3) void bfe12_mfma12_kernel(
    const unsigned short* __restrict__ voxelwise, const int* __restrict__ bevsidx,
    const float* __restrict__ bevmask,
    const short* __restrict__ w1h,
    const float* __restrict__ g1, const float* __restrict__ b1,
    const short* __restrict__ w2ah,
    const float* __restrict__ g2a, const float* __restrict__ b2a,
    const short* __restrict__ w2bh,
    const float* __restrict__ g2b, const float* __restrict__ b2b,
    float* __restrict__ x17buf)
{
  __shared__ short sm[SMEM_SHORTS];
  float* gbf  = (float*)&sm[GB_OFF];      // 2560 floats of gamma/beta
  float* x17f = gbf + GB_FLOATS;          // 4*132 floats

  const int tid  = threadIdx.x;
  const int lane = tid & 63;
  const int w    = tid >> 6;          // 0..7
  const int r15  = lane & 15;
  const int q    = lane >> 4;
  const int cellbase = blockIdx.x * 4;

  const int chq   = lane & 3;
  const int v_loc = (lane >> 2) & 3;
  const int vblk  = lane >> 4;
  const int bit0  = v_loc & 1, bit1 = v_loc >> 1;
  const int gcell = w >> 1;           // cell this wave gathers
  const int vb0   = (w & 1) * 2;      // which half of its 64 voxels

  // ---- stage gamma/beta into LDS (once per block) ----
  for (int k = tid; k < GB_FLOATS; k += 512) {
    float v;
    if (k < 1024)      v = g1[k];
    else if (k < 2048) v = b1[k - 1024];
    else if (k < 2176) v = g2a[k - 2048];
    else if (k < 2304) v = b2a[k - 2176];
    else if (k < 2432) v = g2b[k - 2304];
    else               v = b2b[k - 2432];
    gbf[k] = v;
  }

  // ---- one-shot gather: 8 loads in flight, then transpose + swizzled stage
  int idxr[2];
#pragma unroll
  for (int vi = 0; vi < 2; ++vi)
    idxr[vi] = bevsidx[(cellbase + gcell) * 64 + 16 * (vb0 + vi) + 4 * vblk + v_loc];

  uint2 raw[2][4];   // [vi][js]
#pragma unroll
  for (int vi = 0; vi < 2; ++vi)
#pragma unroll
    for (int js = 0; js < 4; ++js)
      raw[vi][js] = *(const uint2*)(voxelwise + (size_t)idxr[vi] * 64 +
                                    16 * js + 4 * chq);

  // ---- hoisted weight loads for BOTH j chains (overlap gather+barrier)
  short8_t W1f[2][2][4];   // [j][c][f]
  short8_t W2af[2][2];     // [j][c]
  short8_t W2bf[2];        // [j]
#pragma unroll
  for (int j = 0; j < 2; ++j) {
    const int g = 8 * j + w;
#pragma unroll
    for (int c = 0; c < 2; ++c)
#pragma unroll
      for (int f = 0; f < 4; ++f) {
        int off = (g * 64 + r15 + 16 * f) * 64 + 32 * c + 8 * q;
        W1f[j][c][f] = *(const short8_t*)&w1h[off];
      }
#pragma unroll
    for (int c = 0; c < 2; ++c) {
      int off = (g * 16 + r15) * 64 + 32 * c + 8 * q;
      W2af[j][c] = *(const short8_t*)&w2ah[off];
    }
    {
      int off = (g * 16 + r15) * 32 + 8 * q;
      W2bf[j] = *(const short8_t*)&w2bh[off];
    }
  }

#pragma unroll
  for (int js = 0; js < 4; ++js)
#pragma unroll
    for (int vi = 0; vi < 2; ++vi) {
      uint2 packed = gather_transpose(raw[vi][js], bit0, bit1);
      const int vb    = vb0 + vi;
      const int ch    = 16 * js + 4 * chq + v_loc;
      const int chunk = (2 * vb + (vblk >> 1)) ^ (ch & 7);
      const int addr  = gcell * XS_CELL + ch * 64 + 8 * chunk + 4 * (vblk & 1);
      *(uint2*)&sm[addr] = packed;
    }

  __syncthreads();   // panels + gamma/beta staged

  const fx4 zacc = {0.f, 0.f, 0.f, 0.f};
  const int cl = r15 >> 2, p = r15 & 3;
  const float bm = bevmask[cellbase + cl];
  const f32x2 bmv = {bm, bm};
  // j0 scratch in the dedicated ACT region; j1 scratch REUSES the panel
  // region (dead after Phase 1; barrier below fences the reuse).
  short* const acthj0 = &sm[ACT_OFF + w * ACT_WS];
  short* const acthj1 = &sm[w * ACT_WS];

  // ---- Phase 1: panel reads + layer-1 MFMAs, BOTH chains ----
  fx4 acc1[2][4];
#pragma unroll
  for (int j = 0; j < 2; ++j) {
    const int g = 8 * j + w;
    const int ch    = 4 * g + p;
    const int sw    = ch & 7;
    const int xbase = cl * XS_CELL + ch * 64;
    short8_t x0 = *(short8_t*)&sm[xbase + 8 * (q ^ sw)];
    short8_t x1 = *(short8_t*)&sm[xbase + 8 * ((4 + q) ^ sw)];
#pragma unroll
    for (int f = 0; f < 4; ++f) {
      fx4 a = __builtin_amdgcn_mfma_f32_16x16x32_bf16(W1f[j][0][f], x0, zacc, 0, 0, 0);
      acc1[j][f] = __builtin_amdgcn_mfma_f32_16x16x32_bf16(W1f[j][1][f], x1, a, 0, 0, 0);
    }
  }

  __syncthreads();   // ALL waves done reading panels -> j1 scratch reuse safe

  // ---- Phase 2: LN1 stats, both chains (interleaved shuffle trees) ----
  float rstd1[2], ms1[2];
#pragma unroll
  for (int j = 0; j < 2; ++j) {
    f32x2 s1v = {0.f, 0.f}, s2v = {0.f, 0.f};
#pragma unroll
    for (int f = 0; f < 4; ++f) {
      f32x2 a01 = __builtin_shufflevector(acc1[j][f], acc1[j][f], 0, 1);
      f32x2 a23 = __builtin_shufflevector(acc1[j][f], acc1[j][f], 2, 3);
      s1v = s1v + a01 + a23;
      s2v = __builtin_elementwise_fma(a01, a01, s2v);
      s2v = __builtin_elementwise_fma(a23, a23, s2v);
    }
    float s1 = s1v[0] + s1v[1], s2 = s2v[0] + s2v[1];
    s1 += __shfl_xor(s1, 16); s1 += __shfl_xor(s1, 32);
    s2 += __shfl_xor(s2, 16); s2 += __shfl_xor(s2, 32);
    float mean = s1 * (1.f / 64.f);
    rstd1[j] = rsqrtf(fmaf(-mean, mean, s2 * (1.f / 64.f)) + EPS);
    ms1[j] = -mean * rstd1[j];
  }

  // ---- Phase 3: LN1-apply + mish + bevmask -> act scratch, both chains ----
#pragma unroll
  for (int j = 0; j < 2; ++j) {
    const int g = 8 * j + w;
    short* const acth = j ? acthj1 : acthj0;
    const f32x2 rs = {rstd1[j], rstd1[j]}, msv = {ms1[j], ms1[j]};
#pragma unroll
    for (int f = 0; f < 4; ++f) {
      float4 gv = *(const float4*)&gbf[g * 64 + 16 * f + 4 * q];
      float4 bv = *(const float4*)&gbf[1024 + g * 64 + 16 * f + 4 * q];
      f32x2 a01 = __builtin_shufflevector(acc1[j][f], acc1[j][f], 0, 1);
      f32x2 a23 = __builtin_shufflevector(acc1[j][f], acc1[j][f], 2, 3);
      f32x2 o01 = mish2(ln2(a01, rs, msv, (f32x2){gv.x, gv.y}, (f32x2){bv.x, bv.y})) * bmv;
      f32x2 o23 = mish2(ln2(a23, rs, msv, (f32x2){gv.z, gv.w}, (f32x2){bv.z, bv.w})) * bmv;
      *(uint2*)&acth[r15 * 72 + 16 * f + 4 * q] =
          make_uint2(bfpair(o01[0], o01[1]), bfpair(o23[0], o23[1]));
    }
  }

  // ---- Phase 4: act reads (both) -> pad zeros (both) -> layer-2 MFMAs ----
  // per-wave DS program order guarantees reads complete before the zeros.
  short8_t a0r0 = *(short8_t*)&acthj0[r15 * 72 + 8 * q];
  short8_t a1r0 = *(short8_t*)&acthj0[r15 * 72 + 32 + 8 * q];
  short8_t a0r1 = *(short8_t*)&acthj1[r15 * 72 + 8 * q];
  short8_t a1r1 = *(short8_t*)&acthj1[r15 * 72 + 32 + 8 * q];
  if (lane < 60) {
    *(uint2*)&acthj0[160 + 8 * lane] = make_uint2(0u, 0u);
    *(uint2*)&acthj1[160 + 8 * lane] = make_uint2(0u, 0u);
  }
  fx4 a2[2];
  {
    fx4 t0 = __builtin_amdgcn_mfma_f32_16x16x32_bf16(W2af[0][0], a0r0, zacc, 0, 0, 0);
    fx4 t1 = __builtin_amdgcn_mfma_f32_16x16x32_bf16(W2af[1][0], a0r1, zacc, 0, 0, 0);
    a2[0] = __builtin_amdgcn_mfma_f32_16x16x32_bf16(W2af[0][1], a1r0, t0, 0, 0, 0);
    a2[1] = __builtin_amdgcn_mfma_f32_16x16x32_bf16(W2af[1][1], a1r1, t1, 0, 0, 0);
  }

  // ---- Phase 5: LN2 stats (both) + h2h writes (both, q<2) ----
  float rstd2[2], ms2[2];
#pragma unroll
  for (int j = 0; j < 2; ++j) {
    float sa = a2[j][0] + a2[j][1] + a2[j][2] + a2[j][3];
    float sb = fmaf(a2[j][0], a2[j][0], fmaf(a2[j][1], a2[j][1],
               fmaf(a2[j][2], a2[j][2], a2[j][3] * a2[j][3])));
    sa += __shfl_xor(sa, 16); sb += __shfl_xor(sb, 16);
    float mean2 = sa * 0.125f;
    rstd2[j] = rsqrtf(fmaf(-mean2, mean2, sb * 0.125f) + EPS);
    ms2[j] = -mean2 * rstd2[j];
  }
  if (q < 2) {
#pragma unroll
    for (int j = 0; j < 2; ++j) {
      const int g = 8 * j + w;
      short* const h2h = j ? acthj1 : acthj0;
      const f32x2 rs2 = {rstd2[j], rstd2[j]}, ms2v = {ms2[j], ms2[j]};
      float4 gv = *(const float4*)&gbf[2048 + g * 8 + 4 * q];
      float4 bv = *(const float4*)&gbf[2176 + g * 8 + 4 * q];
      f32x2 o01 = mish2(ln2((f32x2){a2[j][0], a2[j][1]}, rs2, ms2v,
                            (f32x2){gv.x, gv.y}, (f32x2){bv.x, bv.y}));
      f32x2 o23 = mish2(ln2((f32x2){a2[j][2], a2[j][3]}, rs2, ms2v,
                            (f32x2){gv.z, gv.w}, (f32x2){bv.z, bv.w}));
      *(uint2*)&h2h[cl * 40 + p * 8 + 4 * q] =
          make_uint2(bfpair(o01[0], o01[1]), bfpair(o23[0], o23[1]));
    }
  }

  // ---- Phase 6: bh reads + layer-3 MFMAs (both) ----
  short8_t bhr0 = *(short8_t*)&acthj0[r15 * 40 + 8 * q];
  short8_t bhr1 = *(short8_t*)&acthj1[r15 * 40 + 8 * q];
  fx4 a3[2];
  a3[0] = __builtin_amdgcn_mfma_f32_16x16x32_bf16(W2bf[0], bhr0, zacc, 0, 0, 0);
  a3[1] = __builtin_amdgcn_mfma_f32_16x16x32_bf16(W2bf[1], bhr1, zacc, 0, 0, 0);

  // ---- Phase 7: LN3 stats (both) + x17f writes ----
  float rstd3[2], ms3[2];
#pragma unroll
  for (int j = 0; j < 2; ++j) {
    float sa = a3[j][0] + a3[j][1] + a3[j][2] + a3[j][3];
    float sb = fmaf(a3[j][0], a3[j][0], fmaf(a3[j][1], a3[j][1],
               fmaf(a3[j][2], a3[j][2], a3[j][3] * a3[j][3])));
    sa += __shfl_xor(sa, 16); sb += __shfl_xor(sb, 16);
    float mean3 = sa * 0.125f;
    rstd3[j] = rsqrtf(fmaf(-mean3, mean3, sb * 0.125f) + EPS);
    ms3[j] = -mean3 * rstd3[j];
  }
  if (q < 2 && r15 < 4) {
#pragma unroll
    for (int j = 0; j < 2; ++j) {
      const int g = 8 * j + w;
      const f32x2 rs3 = {rstd3[j], rstd3[j]}, ms3v = {ms3[j], ms3[j]};
      float4 gv = *(const float4*)&gbf[2304 + g * 8 + 4 * q];
      float4 bv = *(const float4*)&gbf[2432 + g * 8 + 4 * q];
      f32x2 o01 = mish2(ln2((f32x2){a3[j][0], a3[j][1]}, rs3, ms3v,
                            (f32x2){gv.x, gv.y}, (f32x2){bv.x, bv.y}));
      f32x2 o23 = mish2(ln2((f32x2){a3[j][2], a3[j][3]}, rs3, ms3v,
                            (f32x2){gv.z, gv.w}, (f32x2){bv.z, bv.w}));
      float4 outv = {o01[0], o01[1], o23[0], o23[1]};
      *(float4*)&x17f[r15 * 132 + g * 8 + 4 * q] = outv;
    }
  }

  // ---- coalesced x17 dump: 128 float4 stores (4 cells x 128 floats) ----
  __syncthreads();
  if (tid < 128) {
    const int cell = tid >> 5;          // 0..3
    const int off  = (tid & 31) * 4;    // 0..124
    float4 vq = *(const float4*)&x17f[cell * 132 + off];
    *(float4*)&x17buf[(size_t)(cellbase + cell) * 128 + off] = vq;
  }
}

// ---------------------------------------------------------------------------
// Kernel 3 v5 (unchanged): 1-wave/16-cell grid + packed-f32 epilogues.
// ---------------------------------------------------------------------------
__global__ __launch_bounds__(64, 4) void bfe3_mfma5_kernel(
    const float* __restrict__ x17buf,
    const short* __restrict__ w3h, const short* __restrict__ w3l,
    const float* __restrict__ g3, const float* __restrict__ b3,
    float* __restrict__ x19c)
{
  __shared__ short xh18[16 * 136];
  __shared__ short xl18[16 * 136];

  const int tid  = threadIdx.x;
  const int lane = tid & 63;
  const int r15  = lane & 15;
  const int q    = lane >> 4;
  const int cell = blockIdx.x * 16 + r15;
  const float* xr = x17buf + (size_t)cell * 128;
  const fx4 zacc = {0.f, 0.f, 0.f, 0.f};

  short8_t xh[4], xl[4];
#pragma unroll
  for (int c = 0; c < 4; ++c) {
    const float* s = xr + 32 * c + 8 * q;
    float4 A = *(const float4*)s;
    float4 B = *(const float4*)(s + 4);
    float t[8] = {A.x, A.y, A.z, A.w, B.x, B.y, B.z, B.w};
    unsigned hu[4], lu[4];
#pragma unroll
    for (int jj = 0; jj < 4; ++jj) {
      float la, lb;
      hu[jj] = hipack(t[2 * jj], t[2 * jj + 1], la, lb);
      lu[jj] = bfpair(la, lb);
    }
    xh[c] = __builtin_bit_cast(short8_t, make_uint4(hu[0], hu[1], hu[2], hu[3]));
    xl[c] = __builtin_bit_cast(short8_t, make_uint4(lu[0], lu[1], lu[2], lu[3]));
  }

  fx4 acc[8];
#pragma unroll
  for (int f = 0; f < 8; ++f) {
    fx4 a = zacc;
#pragma unroll
    for (int c = 0; c < 4; ++c) {
      int off = (16 * f + r15) * 128 + 32 * c + 8 * q;
      short8_t Ah = *(const short8_t*)&w3h[off];
      short8_t Al = *(const short8_t*)&w3l[off];
      a = __builtin_amdgcn_mfma_f32_16x16x32_bf16(Ah, xh[c], a, 0, 0, 0);
      a = __builtin_amdgcn_mfma_f32_16x16x32_bf16(Ah, xl[c], a, 0, 0, 0);
      a = __builtin_amdgcn_mfma_f32_16x16x32_bf16(Al, xh[c], a, 0, 0, 0);
    }
    acc[f] = a;
  }
  {
    f32x2 s1v = {0.f, 0.f}, s2v = {0.f, 0.f};
#pragma unroll
    for (int f = 0; f < 8; ++f) {
      f32x2 a01 = __builtin_shufflevector(acc[f], acc[f], 0, 1);
      f32x2 a23 = __builtin_shufflevector(acc[f], acc[f], 2, 3);
      s1v = s1v + a01 + a23;
      s2v = __builtin_elementwise_fma(a01, a01, s2v);
      s2v = __builtin_elementwise_fma(a23, a23, s2v);
    }
    float s1 = s1v[0] + s1v[1], s2 = s2v[0] + s2v[1];
    s1 += __shfl_xor(s1, 16); s1 += __shfl_xor(s1, 32);
    s2 += __shfl_xor(s2, 16); s2 += __shfl_xor(s2, 32);
    float mean = s1 * (1.f / 128.f);
    float rstd = rsqrtf(fmaf(-mean, mean, s2 * (1.f / 128.f)) + EPS);
    float ms = -mean * rstd;
    const f32x2 rs = {rstd, rstd}, msv = {ms, ms};
#pragma unroll
    for (int f = 0; f < 8; ++f) {
      float4 gv = *(const float4*)(g3 + 16 * f + 4 * q);
      float4 bv = *(const float4*)(b3 + 16 * f + 4 * q);
      f32x2 a01 = __builtin_shufflevector(acc[f], acc[f], 0, 1);
      f32x2 a23 = __builtin_shufflevector(acc[f], acc[f], 2, 3);
      f32x2 o01 = mish2(ln2(a01, rs, msv, (f32x2){gv.x, gv.y}, (f32x2){bv.x, bv.y}));
      f32x2 o23 = mish2(ln2(a23, rs, msv, (f32x2){gv.z, gv.w}, (f32x2){bv.z, bv.w}));
      float la0, lb0, la1, lb1;
      unsigned h01 = hipack(o01[0], o01[1], la0, lb0);
      unsigned h23 = hipack(o23[0], o23[1], la1, lb1);
      *(uint2*)&xh18[r15 * 136 + 16 * f + 4 * q] = make_uint2(h01, h23);
      *(uint2*)&xl18[r15 * 136 + 16 * f + 4 * q] =
          make_uint2(bfpair(la0, lb0), bfpair(la1, lb1));
    }
  }

  short8_t yh[4], yl[4];
#pragma unroll
  for (int c = 0; c < 4; ++c) {
    yh[c] = *(short8_t*)&xh18[r15 * 136 + 32 * c + 8 * q];
    yl[c] = *(short8_t*)&xl18[r15 * 136 + 32 * c + 8 * q];
  }
#pragma unroll
  for (int f = 0; f < 8; ++f) {
    fx4 a = zacc;
#pragma unroll
    for (int c = 0; c < 4; ++c) {
      int off = (16 * f + r15) * 128 + 32 * c + 8 * q;
      short8_t Ah = *(const short8_t*)&w3h[off];
      short8_t Al = *(const short8_t*)&w3l[off];
      a = __builtin_amdgcn_mfma_f32_16x16x32_bf16(Ah, yh[c], a, 0, 0, 0);
      a = __builtin_amdgcn_mfma_f32_16x16x32_bf16(Ah, yl[c], a, 0, 0, 0);
      a = __builtin_amdgcn_mfma_f32_16x16x32_bf16(Al, yh[c], a, 0, 0, 0);
    }
    acc[f] = a;
  }
  {
    f32x2 s1v = {0.f, 0.f}, s2v = {0.f, 0.f};
#pragma unroll
    for (int f = 0; f < 8; ++f) {
      f32x2 a01 = __builtin_shufflevector(acc[f], acc[f], 0, 1);
      f32x2 a23 = __builtin_shufflevector(acc[f], acc[f], 2, 3);
      s1v = s1v + a01 + a23;
      s2v = __builtin_elementwise_fma(a01, a01, s2v);
      s2v = __builtin_elementwise_fma(a23, a23, s2v);
    }
    float s1 = s1v[0] + s1v[1], s2 = s2v[0] + s2v[1];
    s1 += __shfl_xor(s1, 16); s1 += __shfl_xor(s1, 32);
    s2 += __shfl_xor(s2, 16); s2 += __shfl_xor(s2, 32);
    float mean = s1 * (1.f / 128.f);
    float rstd = rsqrtf(fmaf(-mean, mean, s2 * (1.f / 128.f)) + EPS);
    float ms = -mean * rstd;
    const f32x2 rs = {rstd, rstd}, msv = {ms, ms};

#pragma unroll
    for (int f = 0; f < 8; ++f) {
      float4 gv = *(const float4*)(g3 + 16 * f + 4 * q);
      float4 bv = *(const float4*)(b3 + 16 * f + 4 * q);
      float4 R = *(const float4*)(xr + 16 * f + 4 * q);
      f32x2 a01 = __builtin_shufflevector(acc[f], acc[f], 0, 1);
      f32x2 a23 = __builtin_shufflevector(acc[f], acc[f], 2, 3);
      f32x2 o01 = mish2(ln2(a01, rs, msv, (f32x2){gv.x, gv.y}, (f32x2){bv.x, bv.y}))
                  + (f32x2){R.x, R.y};
      f32x2 o23 = mish2(ln2(a23, rs, msv, (f32x2){gv.z, gv.w}, (f32x2){bv.z, bv.w}))
                  + (f32x2){R.z, R.w};
      float4 ov = {o01[0], o01[1], o23[0], o23[1]};
      *(float4*)&x19c[(size_t)cell * 128 + 16 * f + 4 * q] = ov;
    }
  }
}

// ---------------------------------------------------------------------------
// Expand v2 (unchanged): transposed tile, float4 write phase.
// ---------------------------------------------------------------------------
__global__ __launch_bounds__(256) void expand_kernel(
    const float* __restrict__ x19c, const int* __restrict__ invmap,
    float* __restrict__ out)
{
  __shared__ float tile[128][68];   // 34816 B
  const int tid   = threadIdx.x;
  const int pbase = blockIdx.x * 64;
  const int r     = tid & 63;      // pos within tile
  const int part  = tid >> 6;      // quarter of the 128-ch row
  const int cell  = invmap[pbase + r];
  if (cell >= 0) {
    const float* src = x19c + (size_t)cell * 128 + part * 32;
#pragma unroll
    for (int k = 0; k < 8; ++k) {
      float4 v = *(const float4*)(src + 4 * k);
      tile[part * 32 + 4 * k + 0][r] = v.x;
      tile[part * 32 + 4 * k + 1][r] = v.y;
      tile[part * 32 + 4 * k + 2][r] = v.z;
      tile[part * 32 + 4 * k + 3][r] = v.w;
    }
  } else {
#pragma unroll
    for (int k = 0; k < 32; ++k) tile[part * 32 + k][r] = 0.f;
  }
  __syncthreads();
  // write phase: 2048 float4 units / 256 threads = 8 iterations
#pragma unroll
  for (int k = 0; k < 8; ++k) {
    int unit = k * 256 + tid;        // 0..2047
    int c    = unit >> 4;            // 0..127
    int quad = unit & 15;            // 0..15
    float4 v = *(const float4*)&tile[c][quad * 4];
    *(float4*)&out[(size_t)c * HW + pbase + quad * 4] = v;
  }
}

// ---------------------------------------------------------------------------
extern "C" void kernel_launch(void* const* d_in, const int* in_sizes, int n_in,
                              void* d_out, int out_size, void* d_ws, size_t ws_size,
                              hipStream_t stream) {
  const float* voxels   = (const float*)d_in[0];
  const float* vmask    = (const float*)d_in[1];
  const int*   bevsidx  = (const int*)d_in[2];
  const int*   bevcoors = (const int*)d_in[3];
  const float* bevmask  = (const float*)d_in[4];
  const float* vfe1_W = (const float*)d_in[5];
  const float* vfe1_g = (const float*)d_in[6];
  const float* vfe1_b = (const float*)d_in[7];
  const float* vfe2_W = (const float*)d_in[8];
  const float* vfe2_g = (const float*)d_in[9];
  const float* vfe2_b = (const float*)d_in[10];
  const float* vfe3_W = (const float*)d_in[11];
  const float* vfe3_g = (const float*)d_in[12];
  const float* vfe3_b = (const float*)d_in[13];
  const float* vfe4_W = (const float*)d_in[14];
  const float* vfe4_g = (const float*)d_in[15];
  const float* vfe4_b = (const float*)d_in[16];
  const float* bfe1_W  = (const float*)d_in[17];
  const float* bfe1_g  = (const float*)d_in[18];
  const float* bfe1_b  = (const float*)d_in[19];
  const float* bfe2a_W = (const float*)d_in[20];
  const float* bfe2a_g = (const float*)d_in[21];
  const float* bfe2a_b = (const float*)d_in[22];
  const float* bfe2b_W = (const float*)d_in[23];
  const float* bfe2b_g = (const float*)d_in[24];
  const float* bfe2b_b = (const float*)d_in[25];
  const float* bfe3_W  = (const float*)d_in[26];
  const float* bfe3_g  = (const float*)d_in[27];
  const float* bfe3_b  = (const float*)d_in[28];

  unsigned short* voxelwise = (unsigned short*)d_ws;      // NV*64 bf16
  float* x17buf = (float*)(voxelwise + (size_t)NV * 64);  // NB*128 floats
  float* x19c   = x17buf + (size_t)NB * 128;              // NB*128 floats
  int*   invmap = (int*)(x19c + (size_t)NB * 128);        // HW ints
  short* wbase  = (short*)(invmap + HW);
  short* w1h  = wbase;                                // 65536
  short* w2ah = w1h + 65536;                          // 16384
  short* w2bh = w2ah + 16384;                         // 8192
  short* w3h  = w2bh + 8192;                          // 16384
  short* w3l  = w3h + 16384;                          // 16384
  float* out = (float*)d_out;

  // clear only the 857 KB inverse map (out is fully written by expand_kernel)
  hipMemsetAsync(invmap, 0xFF, (size_t)HW * sizeof(int), stream);

  // fused vfe + weight-pack
  vfe_pack_kernel<<<VFE_BLOCKS + PACK_BLOCKS, 512, 0, stream>>>(
      voxels, vmask,
      vfe1_W, vfe1_g, vfe1_b, vfe2_W, vfe2_g, vfe2_b,
      vfe3_W, vfe3_g, vfe3_b, vfe4_W, vfe4_g, vfe4_b,
      voxelwise,
      bfe1_W, bfe2a_W, bfe2b_W, bfe3_W, bevcoors,
      w1h, w2ah, w2bh, w3h, w3l, invmap);

  bfe12_mfma12_kernel<<<NB / 4, 512, 0, stream>>>(
      voxelwise, bevsidx, bevmask,
      w1h, bfe1_g, bfe1_b,
      w2ah, bfe2a_g, bfe2a_b,
      w2bh, bfe2b_g, bfe2b_b,
      x17buf);

  bfe3_mfma5_kernel<<<NB / 16, 64, 0, stream>>>(
      x17buf, w3h, w3l, bfe3_g, bfe3_b, x19c);

  expand_kernel<<<HW / 64, 256, 0, stream>>>(x19c, invmap, out);
}

// Round 14
// 392.720 us; speedup vs baseline: 1.1665x; 1.1665x over previous
//
#include <hip/hip_runtime.h>
#include <math.h>

// Problem constants (from reference setup_inputs)
constexpr int NV  = 16000;   // voxels
constexpr int P   = 32;      // points per voxel
constexpr int CIN = 10;      // input channels
constexpr int CV  = 64;      // voxel feature channels
constexpr int NB  = 16000;   // BEV cells
constexpr int BEV_H = 496, BEV_W = 432;
constexpr int HW = BEV_H * BEV_W;  // 214272
constexpr float EPS = 1e-5f;

typedef __attribute__((ext_vector_type(8))) short short8_t;  // 8 bf16 (4 VGPR)
typedef __attribute__((ext_vector_type(4))) short short4_t;  // 4 bf16
typedef __attribute__((ext_vector_type(4))) float fx4;       // MFMA C/D frag
typedef __attribute__((ext_vector_type(2))) float f32x2;     // packed f32 pair

// 8-op mish: tanh(softplus(x)) = 1 - 2/((1+e^x)^2+1)  ->  mish = x - 2x/d
__device__ __forceinline__ float mish(float x) {
  float e = __expf(fminf(x, 15.f));
  float u = 1.f + e;
  float d = fmaf(u, u, 1.f);
  float r = __builtin_amdgcn_rcpf(d);
  return fmaf(-2.f * x, r, x);
}

// packed-pair mish: v_pk_* for the mul/add/fma lattice, scalar exp/rcp.
// Bit-identical to scalar mish applied per element.
__device__ __forceinline__ f32x2 mish2(f32x2 x) {
  f32x2 xc = __builtin_elementwise_min(x, (f32x2){15.f, 15.f});
  f32x2 e  = { __expf(xc[0]), __expf(xc[1]) };
  f32x2 u  = e + (f32x2){1.f, 1.f};
  f32x2 d  = __builtin_elementwise_fma(u, u, (f32x2){1.f, 1.f});
  f32x2 r  = { __builtin_amdgcn_rcpf(d[0]), __builtin_amdgcn_rcpf(d[1]) };
  f32x2 m2x = x * (f32x2){-2.f, -2.f};
  return __builtin_elementwise_fma(m2x, r, x);
}
// packed LN apply: (a*rstd + ms)*g + b  (two v_pk_fma)
__device__ __forceinline__ f32x2 ln2(f32x2 a, f32x2 rs, f32x2 msv, f32x2 go, f32x2 bo) {
  return __builtin_elementwise_fma(__builtin_elementwise_fma(a, rs, msv), go, bo);
}

// RNE f32->bf16 (cold paths: weight packing)
__device__ __forceinline__ short f2bf(float f) {
  unsigned u = __builtin_bit_cast(unsigned, f);
  u += 0x7FFF + ((u >> 16) & 1);
  return (short)(u >> 16);
}
__device__ __forceinline__ float bf2f(short s) {
  unsigned u = ((unsigned)(unsigned short)s) << 16;
  return __builtin_bit_cast(float, u);
}
__device__ __forceinline__ short8_t pack8(const float* t) {
  short8_t s;
#pragma unroll
  for (int j = 0; j < 8; ++j) s[j] = f2bf(t[j]);
  return s;
}

// hot-path pack: round-half-up + v_perm pair  (low16 = bf16(a), high16 = bf16(b))
__device__ __forceinline__ unsigned bfpair(float a, float b) {
  unsigned au = __builtin_bit_cast(unsigned, a) + 0x8000u;
  unsigned bu = __builtin_bit_cast(unsigned, b) + 0x8000u;
  return __builtin_amdgcn_perm(bu, au, 0x07060302u);
}
// Dekker-style split pair: returns hi-pack, writes exact lo residuals
__device__ __forceinline__ unsigned hipack(float a, float b, float& la, float& lb) {
  unsigned ua = (__builtin_bit_cast(unsigned, a) + 0x8000u) & 0xFFFF0000u;
  unsigned ub = (__builtin_bit_cast(unsigned, b) + 0x8000u) & 0xFFFF0000u;
  la = a - __builtin_bit_cast(float, ua);
  lb = b - __builtin_bit_cast(float, ub);
  return __builtin_amdgcn_perm(ub, ua, 0x07060302u);
}

// ---------------------------------------------------------------------------
// Fused VFE + weight-pack kernel. Blocks [0, NV/16) run the VFE v8 path
// (half-split, bf16 pairbuf, packed-f32 epilogues). Blocks
// [NV/16, NV/16+208) run the weight-pack + invmap-scatter path
// (208 x 512 = 106496 threads, exact original coverage).
// ---------------------------------------------------------------------------
constexpr int VFE_BLOCKS  = NV / 16;   // 1000
constexpr int PACK_BLOCKS = 208;       // 208*512 = 106496

__global__ __launch_bounds__(512, 4) void vfe_pack_kernel(
    const float* __restrict__ voxels, const float* __restrict__ vmask,
    const float* __restrict__ W1, const float* __restrict__ g1, const float* __restrict__ b1,
    const float* __restrict__ W2, const float* __restrict__ g2, const float* __restrict__ b2,
    const float* __restrict__ W3, const float* __restrict__ g3, const float* __restrict__ b3,
    const float* __restrict__ W4, const float* __restrict__ g4, const float* __restrict__ b4,
    unsigned short* __restrict__ voxelwise,
    const float* __restrict__ bW1, const float* __restrict__ bW2a,
    const float* __restrict__ bW2b, const float* __restrict__ bW3,
    const int* __restrict__ bevcoors,
    short* __restrict__ w1h, short* __restrict__ w2ah, short* __restrict__ w2bh,
    short* __restrict__ w3h, short* __restrict__ w3l,
    int* __restrict__ invmap)
{
  __shared__ short wlds[28 * 512];                 // 28672 B
  __shared__ short actb[8][16 * 72];               // 18432 B (wave-private act buf)
  __shared__ float gblds[512];                     //  2048 B
  __shared__ unsigned short pairbuf[2][4][4][64];  //  4096 B bf16

  const int tid = threadIdx.x;

  // ---------------- pack path (blocks >= VFE_BLOCKS) ----------------
  if (blockIdx.x >= VFE_BLOCKS) {
    int i = (blockIdx.x - VFE_BLOCKS) * 512 + tid;
    if (i < NB) {
      int2 hw2 = *(const int2*)&bevcoors[i * 2];   // (h, w)
      invmap[hw2.y * BEV_H + hw2.x] = i;
    }
    if (i < 65536) {
      w1h[i] = f2bf(bW1[i]);
    } else if (i < 81920) {
      int j = i - 65536;
      int g = j >> 10, o = (j >> 6) & 15, c = j & 63;
      float v = (o < 8) ? bW2a[(g * 8 + o) * 64 + c] : 0.f;
      w2ah[j] = f2bf(v);
    } else if (i < 90112) {
      int k = i - 81920;
      int g = k >> 9, o = (k >> 5) & 15, c = k & 31;
      float v = (o < 8) ? bW2b[(g * 8 + o) * 32 + c] : 0.f;
      w2bh[k] = f2bf(v);
    } else if (i < 106496) {
      int j = i - 90112;
      float v = bW3[j];
      short h = f2bf(v);
      w3h[j] = h; w3l[j] = f2bf(v - bf2f(h));
    }
    return;
  }

  // ---------------- VFE path ----------------
  const int lane = tid & 63;
  const int w    = tid >> 6;      // 0..7
  const int pair = w >> 1;        // 0..3 (voxel group within block)
  const int h    = w & 1;         // which half of the 32 points
  const int p    = lane & 15;
  const int q    = lane >> 4;
  const int gw   = blockIdx.x * 4 + pair;

  {
    int region = tid >> 6, off = tid & 63;
    const float* src =
        region == 0 ? g1 : region == 1 ? b1 :
        region == 2 ? g2 : region == 3 ? b2 :
        region == 4 ? g3 : region == 5 ? b3 :
        region == 6 ? g4 : b4;
    gblds[tid] = src[off];
  }
  for (int s = w; s < 28; s += 8) {
    float t[8];
    if (s < 4) {
      const int f = s;
#pragma unroll
      for (int j = 0; j < 8; ++j) {
        int c = 8 * q + j;
        t[j] = (c < CIN) ? W1[(p + 16 * f) * CIN + c] : 0.f;
      }
    } else {
      const int l = (s - 4) >> 3, rem = (s - 4) & 7, ch = rem >> 2, f = rem & 3;
      const float* Wl = (l == 0) ? W2 : (l == 1) ? W3 : W4;
      const float* src = Wl + (p + 16 * f) * CV + 32 * ch + 8 * q;
#pragma unroll
      for (int j = 0; j < 8; ++j) t[j] = src[j];
    }
    *(short8_t*)&wlds[s * 512 + lane * 8] = pack8(t);
  }
  __syncthreads();

  short* mybuf = &actb[w][0];
  const fx4 zacc = {0.f, 0.f, 0.f, 0.f};
  const int srcLane = ((lane >> 2) & 3) * 16 + (((lane >> 4) & 3) << 2) + (lane & 3);

  for (int i = 0; i < 4; ++i) {
    const int v = gw * 4 + i;
    const int ptbase = v * 32 + h * 16;
    const float m = vmask[ptbase + p];
    const f32x2 mv = {m, m};
    f32x2 x2r2[8];
    float cur[16];

    // ---- layer 1 ----
    {
      const float* xrow = voxels + (size_t)(ptbase + p) * CIN;
      float t[8] = {0.f, 0.f, 0.f, 0.f, 0.f, 0.f, 0.f, 0.f};
      if (q == 0) {
        float2 a = *(const float2*)(xrow + 0);
        float2 b = *(const float2*)(xrow + 2);
        float2 c = *(const float2*)(xrow + 4);
        float2 d = *(const float2*)(xrow + 6);
        t[0] = a.x; t[1] = a.y; t[2] = b.x; t[3] = b.y;
        t[4] = c.x; t[5] = c.y; t[6] = d.x; t[7] = d.y;
      } else if (q == 1) {
        float2 a = *(const float2*)(xrow + 8);
        t[0] = a.x; t[1] = a.y;
      }
      uint4 bu = make_uint4(bfpair(t[0], t[1]), bfpair(t[2], t[3]),
                            bfpair(t[4], t[5]), bfpair(t[6], t[7]));
      short8_t bfrag = __builtin_bit_cast(short8_t, bu);
      fx4 acc[4];
#pragma unroll
      for (int f = 0; f < 4; ++f) {
        short8_t af = *(short8_t*)&wlds[f * 512 + lane * 8];
        acc[f] = __builtin_amdgcn_mfma_f32_16x16x32_bf16(af, bfrag, zacc, 0, 0, 0);
      }
      f32x2 s1v = {0.f, 0.f}, s2v = {0.f, 0.f};
#pragma unroll
      for (int f = 0; f < 4; ++f) {
        f32x2 a01 = __builtin_shufflevector(acc[f], acc[f], 0, 1);
        f32x2 a23 = __builtin_shufflevector(acc[f], acc[f], 2, 3);
        s1v = s1v + a01 + a23;
        s2v = __builtin_elementwise_fma(a01, a01, s2v);
        s2v = __builtin_elementwise_fma(a23, a23, s2v);
      }
      float s1 = s1v[0] + s1v[1], s2 = s2v[0] + s2v[1];
      s1 += __shfl_xor(s1, 16); s1 += __shfl_xor(s1, 32);
      s2 += __shfl_xor(s2, 16); s2 += __shfl_xor(s2, 32);
      float mean = s1 * (1.f / 64.f);
      float rstd = rsqrtf(fmaf(-mean, mean, s2 * (1.f / 64.f)) + EPS);
      float ms = -mean * rstd;
      const f32x2 rs = {rstd, rstd}, msv = {ms, ms};
#pragma unroll
      for (int f = 0; f < 4; ++f) {
        float4 gv = *(const float4*)&gblds[16 * f + 4 * q];
        float4 bv = *(const float4*)&gblds[64 + 16 * f + 4 * q];
        f32x2 a01 = __builtin_shufflevector(acc[f], acc[f], 0, 1);
        f32x2 a23 = __builtin_shufflevector(acc[f], acc[f], 2, 3);
        f32x2 o01 = mish2(ln2(a01, rs, msv, (f32x2){gv.x, gv.y}, (f32x2){bv.x, bv.y}));
        f32x2 o23 = mish2(ln2(a23, rs, msv, (f32x2){gv.z, gv.w}, (f32x2){bv.z, bv.w}));
        *(uint2*)&mybuf[p * 72 + 4 * q + 16 * f] =
            make_uint2(bfpair(o01[0], o01[1]), bfpair(o23[0], o23[1]));
      }
    }

    // ---- layers 2..4 ----
#pragma unroll 1
    for (int l = 0; l < 3; ++l) {
      short8_t bf0 = *(short8_t*)&mybuf[p * 72 + 8 * q];
      short8_t bf1 = *(short8_t*)&mybuf[p * 72 + 8 * q + 32];
      fx4 acc[4];
#pragma unroll
      for (int f = 0; f < 4; ++f) {
        short8_t a0 = *(short8_t*)&wlds[(4 + l * 8 + f) * 512 + lane * 8];
        short8_t a1 = *(short8_t*)&wlds[(4 + l * 8 + 4 + f) * 512 + lane * 8];
        fx4 a = __builtin_amdgcn_mfma_f32_16x16x32_bf16(a0, bf0, zacc, 0, 0, 0);
        acc[f] = __builtin_amdgcn_mfma_f32_16x16x32_bf16(a1, bf1, a, 0, 0, 0);
      }
      f32x2 s1v = {0.f, 0.f}, s2v = {0.f, 0.f};
#pragma unroll
      for (int f = 0; f < 4; ++f) {
        f32x2 a01 = __builtin_shufflevector(acc[f], acc[f], 0, 1);
        f32x2 a23 = __builtin_shufflevector(acc[f], acc[f], 2, 3);
        s1v = s1v + a01 + a23;
        s2v = __builtin_elementwise_fma(a01, a01, s2v);
        s2v = __builtin_elementwise_fma(a23, a23, s2v);
      }
      float s1 = s1v[0] + s1v[1], s2 = s2v[0] + s2v[1];
      s1 += __shfl_xor(s1, 16); s1 += __shfl_xor(s1, 32);
      s2 += __shfl_xor(s2, 16); s2 += __shfl_xor(s2, 32);
      float mean = s1 * (1.f / 64.f);
      float rstd = rsqrtf(fmaf(-mean, mean, s2 * (1.f / 64.f)) + EPS);
      float ms = -mean * rstd;
      const f32x2 rs = {rstd, rstd}, msv = {ms, ms};
      const int gbbase = (l + 1) * 128;
#pragma unroll
      for (int f = 0; f < 4; ++f) {
        float4 gv = *(const float4*)&gblds[gbbase + 16 * f + 4 * q];
        float4 bv = *(const float4*)&gblds[gbbase + 64 + 16 * f + 4 * q];
        f32x2 go01 = {gv.x, gv.y}, go23 = {gv.z, gv.w};
        f32x2 bo01 = {bv.x, bv.y}, bo23 = {bv.z, bv.w};
        f32x2 a01 = __builtin_shufflevector(acc[f], acc[f], 0, 1);
        f32x2 a23 = __builtin_shufflevector(acc[f], acc[f], 2, 3);
        if (l == 0) {
          f32x2 o01 = mish2(ln2(a01, rs, msv, go01, bo01)) * mv;
          f32x2 o23 = mish2(ln2(a23, rs, msv, go23, bo23)) * mv;
          x2r2[2 * f] = o01; x2r2[2 * f + 1] = o23;
          *(uint2*)&mybuf[p * 72 + 4 * q + 16 * f] =
              make_uint2(bfpair(o01[0], o01[1]), bfpair(o23[0], o23[1]));
        } else if (l == 1) {
          f32x2 o01 = mish2(ln2(a01, rs, msv, go01, bo01));
          f32x2 o23 = mish2(ln2(a23, rs, msv, go23, bo23));
          *(uint2*)&mybuf[p * 72 + 4 * q + 16 * f] =
              make_uint2(bfpair(o01[0], o01[1]), bfpair(o23[0], o23[1]));
        } else {
          f32x2 c01 = __builtin_elementwise_fma(
              mish2(ln2(a01, rs, msv, go01, bo01)), mv, x2r2[2 * f]);
          f32x2 c23 = __builtin_elementwise_fma(
              mish2(ln2(a23, rs, msv, go23, bo23)), mv, x2r2[2 * f + 1]);
          cur[f * 4 + 0] = c01[0]; cur[f * 4 + 1] = c01[1];
          cur[f * 4 + 2] = c23[0]; cur[f * 4 + 3] = c23[1];
        }
      }
    }

    // ---- reduce-scatter max over 16 points; lane p keeps value j=p ----
#pragma unroll
    for (int t = 0; t < 8; ++t) {
      float send = (lane & 8) ? cur[t] : cur[t + 8];
      float got  = __shfl_xor(send, 8);
      float mine = (lane & 8) ? cur[t + 8] : cur[t];
      cur[t] = fmaxf(mine, got);
    }
#pragma unroll
    for (int t = 0; t < 4; ++t) {
      float send = (lane & 4) ? cur[t] : cur[t + 4];
      float got  = __shfl_xor(send, 4);
      float mine = (lane & 4) ? cur[t + 4] : cur[t];
      cur[t] = fmaxf(mine, got);
    }
#pragma unroll
    for (int t = 0; t < 2; ++t) {
      float send = (lane & 2) ? cur[t] : cur[t + 2];
      float got  = __shfl_xor(send, 2);
      float mine = (lane & 2) ? cur[t + 2] : cur[t];
      cur[t] = fmaxf(mine, got);
    }
    {
      float send = (lane & 1) ? cur[0] : cur[1];
      float got  = __shfl_xor(send, 1);
      float mine = (lane & 1) ? cur[1] : cur[0];
      cur[0] = fmaxf(mine, got);
    }
    float hm = __shfl(cur[0], srcLane);
    // round to bf16 BEFORE the cross-half max (monotonic: identical result)
    unsigned hu = __builtin_bit_cast(unsigned, hm) + 0x8000u;
    pairbuf[h][pair][i][lane] = (unsigned short)(hu >> 16);
  }

  __syncthreads();   // all half-max vectors staged

  if (h == 0) {
#pragma unroll
    for (int i = 0; i < 4; ++i) {
      const int v = gw * 4 + i;
      float a = bf2f((short)pairbuf[0][pair][i][lane]);
      float b = bf2f((short)pairbuf[1][pair][i][lane]);
      float vmaxv = fmaxf(a, b);   // both already bf16; max is exact
      voxelwise[v * 64 + lane] =
          (unsigned short)(__builtin_bit_cast(unsigned, vmaxv) >> 16);
    }
  }
}

// ---------------------------------------------------------------------------
// Kernel 2 v10 (best measured config): packed-f32 epilogues, (512,3).
// ---------------------------------------------------------------------------
constexpr int XS_CELL = 64 * 64 + 16;   // 4112 shorts: swizzled panel + 32B bank stagger
constexpr int ACT_OFF = 4 * XS_CELL;    // 16448
constexpr int ACT_WS  = 16 * 72;        // 1152 shorts per wave (h2 overlaid at offset 0)
constexpr int GB_OFF  = ACT_OFF + 8 * ACT_WS;   // 25664 shorts (51328 B, 16B aligned)
constexpr int GB_FLOATS = 2560;                 // g1,b1 (1024 ea) + g2a,b2a,g2b,b2b (128 ea)
constexpr int SMEM_SHORTS = GB_OFF + 2 * (GB_FLOATS + 4 * 132);  // 31840 shorts = 63680 B

__device__ __forceinline__ uint2 gather_transpose(uint2 u2, int bit0, int bit1) {
  float a0 = __builtin_bit_cast(float, u2.x << 16);
  float a1 = __builtin_bit_cast(float, u2.x & 0xFFFF0000u);
  float a2 = __builtin_bit_cast(float, u2.y << 16);
  float a3 = __builtin_bit_cast(float, u2.y & 0xFFFF0000u);
  float gv0 = bit0 ? a0 : a1, gv1 = bit0 ? a2 : a3;
  float r0 = __shfl_xor(gv0, 4), r1 = __shfl_xor(gv1, 4);
  float c0 = bit0 ? r0 : a0, c1 = bit0 ? a1 : r0;
  float c2 = bit0 ? r1 : a2, c3 = bit0 ? a3 : r1;
  float h0 = bit1 ? c0 : c2, h1 = bit1 ? c1 : c3;
  float s0 = __shfl_xor(h0, 8), s1 = __shfl_xor(h1, 8);
  float d0 = bit1 ? s0 : c0, d1 = bit1 ? s1 : c1;
  float d2 = bit1 ? c2 : s0, d3 = bit1 ? c3 : s1;
  // bfpair exact here (inputs already bf16 bit patterns)
  return make_uint2(bfpair(d0, d1), bfpair(d2, d3));
}

__global__ __launch_bounds__(512, 3) void bfe12_mfma10_kernel(
    const unsigned short* __restrict__ voxelwise, const int* __restrict__ bevsidx,
    const float* __restrict__ bevmask,
    const short* __restrict__ w1h,
    const float* __restrict__ g1, const float* __restrict__ b1,
    const short* __restrict__ w2ah,
    const float* __restrict__ g2a, const float* __restrict__ b2a,
    const short* __restrict__ w2bh,
    const float* __restrict__ g2b, const float* __restrict__ b2b,
    float* __restrict__ x17buf)
{
  __shared__ short sm[SMEM_SHORTS];
  float* gbf  = (float*)&sm[GB_OFF];      // 2560 floats of gamma/beta
  float* x17f = gbf + GB_FLOATS;          // 4*132 floats

  const int tid  = threadIdx.x;
  const int lane = tid & 63;
  const int w    = tid >> 6;          // 0..7
  const int r15  = lane & 15;
  const int q    = lane >> 4;
  const int cellbase = blockIdx.x * 4;

  const int chq   = lane & 3;
  const int v_loc = (lane >> 2) & 3;
  const int vblk  = lane >> 4;
  const int bit0  = v_loc & 1, bit1 = v_loc >> 1;
  const int gcell = w >> 1;           // cell this wave gathers
  const int vb0   = (w & 1) * 2;      // which half of its 64 voxels

  // ---- stage gamma/beta into LDS (once per block) ----
  for (int k = tid; k < GB_FLOATS; k += 512) {
    float v;
    if (k < 1024)      v = g1[k];
    else if (k < 2048) v = b1[k - 1024];
    else if (k < 2176) v = g2a[k - 2048];
    else if (k < 2304) v = b2a[k - 2176];
    else if (k < 2432) v = g2b[k - 2304];
    else               v = b2b[k - 2432];
    gbf[k] = v;
  }

  // ---- one-shot gather: 8 loads in flight, then transpose + swizzled stage
  int idxr[2];
#pragma unroll
  for (int vi = 0; vi < 2; ++vi)
    idxr[vi] = bevsidx[(cellbase + gcell) * 64 + 16 * (vb0 + vi) + 4 * vblk + v_loc];

  uint2 raw[2][4];   // [vi][js]
#pragma unroll
  for (int vi = 0; vi < 2; ++vi)
#pragma unroll
    for (int js = 0; js < 4; ++js)
      raw[vi][js] = *(const uint2*)(voxelwise + (size_t)idxr[vi] * 64 +
                                    16 * js + 4 * chq);

  // ---- hoisted weight loads for BOTH j iterations (overlap gather+barrier)
  short8_t W1f[2][2][4];   // [j][c][f]
  short8_t W2af[2][2];     // [j][c]
  short8_t W2bf[2];        // [j]
#pragma unroll
  for (int j = 0; j < 2; ++j) {
    const int g = 8 * j + w;
#pragma unroll
    for (int c = 0; c < 2; ++c)
#pragma unroll
      for (int f = 0; f < 4; ++f) {
        int off = (g * 64 + r15 + 16 * f) * 64 + 32 * c + 8 * q;
        W1f[j][c][f] = *(const short8_t*)&w1h[off];
      }
#pragma unroll
    for (int c = 0; c < 2; ++c) {
      int off = (g * 16 + r15) * 64 + 32 * c + 8 * q;
      W2af[j][c] = *(const short8_t*)&w2ah[off];
    }
    {
      int off = (g * 16 + r15) * 32 + 8 * q;
      W2bf[j] = *(const short8_t*)&w2bh[off];
    }
  }

#pragma unroll
  for (int js = 0; js < 4; ++js)
#pragma unroll
    for (int vi = 0; vi < 2; ++vi) {
      uint2 packed = gather_transpose(raw[vi][js], bit0, bit1);
      const int vb    = vb0 + vi;
      const int ch    = 16 * js + 4 * chq + v_loc;
      const int chunk = (2 * vb + (vblk >> 1)) ^ (ch & 7);
      const int addr  = gcell * XS_CELL + ch * 64 + 8 * chunk + 4 * (vblk & 1);
      *(uint2*)&sm[addr] = packed;
    }

  __syncthreads();   // panels + gamma/beta staged

  const fx4 zacc = {0.f, 0.f, 0.f, 0.f};
  short* acth = &sm[ACT_OFF + w * ACT_WS];
  short* h2h  = acth;                     // overlaid scratch (sequential lifetimes)
  const int cl = r15 >> 2, p = r15 & 3;
  const float bm = bevmask[cellbase + cl];
  const f32x2 bmv = {bm, bm};

#pragma unroll
  for (int j = 0; j < 2; ++j) {
    const int g = 8 * j + w;

    // ---- single tile: 4 cells x 4 p ----
    {
      const int ch    = 4 * g + p;
      const int sw    = ch & 7;
      const int xbase = cl * XS_CELL + ch * 64;
      short8_t x0 = *(short8_t*)&sm[xbase + 8 * (q ^ sw)];
      short8_t x1 = *(short8_t*)&sm[xbase + 8 * ((4 + q) ^ sw)];

      fx4 acc[4];
#pragma unroll
      for (int f = 0; f < 4; ++f) {
        fx4 a = __builtin_amdgcn_mfma_f32_16x16x32_bf16(W1f[j][0][f], x0, zacc, 0, 0, 0);
        acc[f] = __builtin_amdgcn_mfma_f32_16x16x32_bf16(W1f[j][1][f], x1, a, 0, 0, 0);
      }

      f32x2 s1v = {0.f, 0.f}, s2v = {0.f, 0.f};
#pragma unroll
      for (int f = 0; f < 4; ++f) {
        f32x2 a01 = __builtin_shufflevector(acc[f], acc[f], 0, 1);
        f32x2 a23 = __builtin_shufflevector(acc[f], acc[f], 2, 3);
        s1v = s1v + a01 + a23;
        s2v = __builtin_elementwise_fma(a01, a01, s2v);
        s2v = __builtin_elementwise_fma(a23, a23, s2v);
      }
      float s1 = s1v[0] + s1v[1], s2 = s2v[0] + s2v[1];
      s1 += __shfl_xor(s1, 16); s1 += __shfl_xor(s1, 32);
      s2 += __shfl_xor(s2, 16); s2 += __shfl_xor(s2, 32);
      float mean = s1 * (1.f / 64.f);
      float rstd = rsqrtf(fmaf(-mean, mean, s2 * (1.f / 64.f)) + EPS);
      float ms = -mean * rstd;
      const f32x2 rs = {rstd, rstd}, msv = {ms, ms};

#pragma unroll
      for (int f = 0; f < 4; ++f) {
        float4 gv = *(const float4*)&gbf[g * 64 + 16 * f + 4 * q];
        float4 bv = *(const float4*)&gbf[1024 + g * 64 + 16 * f + 4 * q];
        f32x2 a01 = __builtin_shufflevector(acc[f], acc[f], 0, 1);
        f32x2 a23 = __builtin_shufflevector(acc[f], acc[f], 2, 3);
        f32x2 o01 = mish2(ln2(a01, rs, msv, (f32x2){gv.x, gv.y}, (f32x2){bv.x, bv.y})) * bmv;
        f32x2 o23 = mish2(ln2(a23, rs, msv, (f32x2){gv.z, gv.w}, (f32x2){bv.z, bv.w})) * bmv;
        *(uint2*)&acth[r15 * 72 + 16 * f + 4 * q] =
            make_uint2(bfpair(o01[0], o01[1]), bfpair(o23[0], o23[1]));
      }

      short8_t a0 = *(short8_t*)&acth[r15 * 72 + 8 * q];
      short8_t a1 = *(short8_t*)&acth[r15 * 72 + 32 + 8 * q];

      // re-zero h2 pad rows 4..15 (overlaid region was clobbered by acth);
      // MUST be after the a0/a1 reads above (program-order LDS per wave).
      if (lane < 60) *(uint2*)&h2h[160 + 8 * lane] = make_uint2(0u, 0u);

      fx4 a2 = __builtin_amdgcn_mfma_f32_16x16x32_bf16(W2af[j][0], a0, zacc, 0, 0, 0);
      a2 = __builtin_amdgcn_mfma_f32_16x16x32_bf16(W2af[j][1], a1, a2, 0, 0, 0);

      float sa = a2[0] + a2[1] + a2[2] + a2[3];
      float sb = fmaf(a2[0], a2[0], fmaf(a2[1], a2[1], fmaf(a2[2], a2[2], a2[3] * a2[3])));
      sa += __shfl_xor(sa, 16); sb += __shfl_xor(sb, 16);
      if (q < 2) {
        float mean2 = sa * 0.125f;
        float rstd2 = rsqrtf(fmaf(-mean2, mean2, sb * 0.125f) + EPS);
        float ms2 = -mean2 * rstd2;
        const f32x2 rs2 = {rstd2, rstd2}, ms2v = {ms2, ms2};
        float4 gv = *(const float4*)&gbf[2048 + g * 8 + 4 * q];
        float4 bv = *(const float4*)&gbf[2176 + g * 8 + 4 * q];
        f32x2 o01 = mish2(ln2((f32x2){a2[0], a2[1]}, rs2, ms2v,
                              (f32x2){gv.x, gv.y}, (f32x2){bv.x, bv.y}));
        f32x2 o23 = mish2(ln2((f32x2){a2[2], a2[3]}, rs2, ms2v,
                              (f32x2){gv.z, gv.w}, (f32x2){bv.z, bv.w}));
        *(uint2*)&h2h[cl * 40 + p * 8 + 4 * q] =
            make_uint2(bfpair(o01[0], o01[1]), bfpair(o23[0], o23[1]));
      }
    }

    // ---- bfe2b: rows = 4 cells (+12 zero pad), K=32 ----
    {
      short8_t bh = *(short8_t*)&h2h[r15 * 40 + 8 * q];
      fx4 a3 = __builtin_amdgcn_mfma_f32_16x16x32_bf16(W2bf[j], bh, zacc, 0, 0, 0);

      float sa = a3[0] + a3[1] + a3[2] + a3[3];
      float sb = fmaf(a3[0], a3[0], fmaf(a3[1], a3[1], fmaf(a3[2], a3[2], a3[3] * a3[3])));
      sa += __shfl_xor(sa, 16); sb += __shfl_xor(sb, 16);
      if (q < 2 && r15 < 4) {
        float mean3 = sa * 0.125f;
        float rstd3 = rsqrtf(fmaf(-mean3, mean3, sb * 0.125f) + EPS);
        float ms3 = -mean3 * rstd3;
        const f32x2 rs3 = {rstd3, rstd3}, ms3v = {ms3, ms3};
        float4 gv = *(const float4*)&gbf[2304 + g * 8 + 4 * q];
        float4 bv = *(const float4*)&gbf[2432 + g * 8 + 4 * q];
        f32x2 o01 = mish2(ln2((f32x2){a3[0], a3[1]}, rs3, ms3v,
                              (f32x2){gv.x, gv.y}, (f32x2){bv.x, bv.y}));
        f32x2 o23 = mish2(ln2((f32x2){a3[2], a3[3]}, rs3, ms3v,
                              (f32x2){gv.z, gv.w}, (f32x2){bv.z, bv.w}));
        float4 outv = {o01[0], o01[1], o23[0], o23[1]};
        *(float4*)&x17f[r15 * 132 + g * 8 + 4 * q] = outv;
      }
    }
  }

  // ---- coalesced x17 dump: 128 float4 stores (4 cells x 128 floats) ----
  __syncthreads();
  if (tid < 128) {
    const int cell = tid >> 5;          // 0..3
    const int off  = (tid & 31) * 4;    // 0..124
    float4 vq = *(const float4*)&x17f[cell * 132 + off];
    *(float4*)&x17buf[(size_t)(cellbase + cell) * 128 + off] = vq;
  }
}

// ---------------------------------------------------------------------------
// Kernel 3 v5: 1-wave/16-cell grid + packed-f32 epilogues.
// ---------------------------------------------------------------------------
__global__ __launch_bounds__(64, 4) void bfe3_mfma5_kernel(
    const float* __restrict__ x17buf,
    const short* __restrict__ w3h, const short* __restrict__ w3l,
    const float* __restrict__ g3, const float* __restrict__ b3,
    float* __restrict__ x19c)
{
  __shared__ short xh18[16 * 136];
  __shared__ short xl18[16 * 136];

  const int tid  = threadIdx.x;
  const int lane = tid & 63;
  const int r15  = lane & 15;
  const int q    = lane >> 4;
  const int cell = blockIdx.x * 16 + r15;
  const float* xr = x17buf + (size_t)cell * 128;
  const fx4 zacc = {0.f, 0.f, 0.f, 0.f};

  short8_t xh[4], xl[4];
#pragma unroll
  for (int c = 0; c < 4; ++c) {
    const float* s = xr + 32 * c + 8 * q;
    float4 A = *(const float4*)s;
    float4 B = *(const float4*)(s + 4);
    float t[8] = {A.x, A.y, A.z, A.w, B.x, B.y, B.z, B.w};
    unsigned hu[4], lu[4];
#pragma unroll
    for (int jj = 0; jj < 4; ++jj) {
      float la, lb;
      hu[jj] = hipack(t[2 * jj], t[2 * jj + 1], la, lb);
      lu[jj] = bfpair(la, lb);
    }
    xh[c] = __builtin_bit_cast(short8_t, make_uint4(hu[0], hu[1], hu[2], hu[3]));
    xl[c] = __builtin_bit_cast(short8_t, make_uint4(lu[0], lu[1], lu[2], lu[3]));
  }

  fx4 acc[8];
#pragma unroll
  for (int f = 0; f < 8; ++f) {
    fx4 a = zacc;
#pragma unroll
    for (int c = 0; c < 4; ++c) {
      int off = (16 * f + r15) * 128 + 32 * c + 8 * q;
      short8_t Ah = *(const short8_t*)&w3h[off];
      short8_t Al = *(const short8_t*)&w3l[off];
      a = __builtin_amdgcn_mfma_f32_16x16x32_bf16(Ah, xh[c], a, 0, 0, 0);
      a = __builtin_amdgcn_mfma_f32_16x16x32_bf16(Ah, xl[c], a, 0, 0, 0);
      a = __builtin_amdgcn_mfma_f32_16x16x32_bf16(Al, xh[c], a, 0, 0, 0);
    }
    acc[f] = a;
  }
  {
    f32x2 s1v = {0.f, 0.f}, s2v = {0.f, 0.f};
#pragma unroll
    for (int f = 0; f < 8; ++f) {
      f32x2 a01 = __builtin_shufflevector(acc[f], acc[f], 0, 1);
      f32x2 a23 = __builtin_shufflevector(acc[f], acc[f], 2, 3);
      s1v = s1v + a01 + a23;
      s2v = __builtin_elementwise_fma(a01, a01, s2v);
      s2v = __builtin_elementwise_fma(a23, a23, s2v);
    }
    float s1 = s1v[0] + s1v[1], s2 = s2v[0] + s2v[1];
    s1 += __shfl_xor(s1, 16); s1 += __shfl_xor(s1, 32);
    s2 += __shfl_xor(s2, 16); s2 += __shfl_xor(s2, 32);
    float mean = s1 * (1.f / 128.f);
    float rstd = rsqrtf(fmaf(-mean, mean, s2 * (1.f / 128.f)) + EPS);
    float ms = -mean * rstd;
    const f32x2 rs = {rstd, rstd}, msv = {ms, ms};
#pragma unroll
    for (int f = 0; f < 8; ++f) {
      float4 gv = *(const float4*)(g3 + 16 * f + 4 * q);
      float4 bv = *(const float4*)(b3 + 16 * f + 4 * q);
      f32x2 a01 = __builtin_shufflevector(acc[f], acc[f], 0, 1);
      f32x2 a23 = __builtin_shufflevector(acc[f], acc[f], 2, 3);
      f32x2 o01 = mish2(ln2(a01, rs, msv, (f32x2){gv.x, gv.y}, (f32x2){bv.x, bv.y}));
      f32x2 o23 = mish2(ln2(a23, rs, msv, (f32x2){gv.z, gv.w}, (f32x2){bv.z, bv.w}));
      float la0, lb0, la1, lb1;
      unsigned h01 = hipack(o01[0], o01[1], la0, lb0);
      unsigned h23 = hipack(o23[0], o23[1], la1, lb1);
      *(uint2*)&xh18[r15 * 136 + 16 * f + 4 * q] = make_uint2(h01, h23);
      *(uint2*)&xl18[r15 * 136 + 16 * f + 4 * q] =
          make_uint2(bfpair(la0, lb0), bfpair(la1, lb1));
    }
  }

  short8_t yh[4], yl[4];
#pragma unroll
  for (int c = 0; c < 4; ++c) {
    yh[c] = *(short8_t*)&xh18[r15 * 136 + 32 * c + 8 * q];
    yl[c] = *(short8_t*)&xl18[r15 * 136 + 32 * c + 8 * q];
  }
#pragma unroll
  for (int f = 0; f < 8; ++f) {
    fx4 a = zacc;
#pragma unroll
    for (int c = 0; c < 4; ++c) {
      int off = (16 * f + r15) * 128 + 32 * c + 8 * q;
      short8_t Ah = *(const short8_t*)&w3h[off];
      short8_t Al = *(const short8_t*)&w3l[off];
      a = __builtin_amdgcn_mfma_f32_16x16x32_bf16(Ah, yh[c], a, 0, 0, 0);
      a = __builtin_amdgcn_mfma_f32_16x16x32_bf16(Ah, yl[c], a, 0, 0, 0);
      a = __builtin_amdgcn_mfma_f32_16x16x32_bf16(Al, yh[c], a, 0, 0, 0);
    }
    acc[f] = a;
  }
  {
    f32x2 s1v = {0.f, 0.f}, s2v = {0.f, 0.f};
#pragma unroll
    for (int f = 0; f < 8; ++f) {
      f32x2 a01 = __builtin_shufflevector(acc[f], acc[f], 0, 1);
      f32x2 a23 = __builtin_shufflevector(acc[f], acc[f], 2, 3);
      s1v = s1v + a01 + a23;
      s2v = __builtin_elementwise_fma(a01, a01, s2v);
      s2v = __builtin_elementwise_fma(a23, a23, s2v);
    }
    float s1 = s1v[0] + s1v[1], s2 = s2v[0] + s2v[1];
    s1 += __shfl_xor(s1, 16); s1 += __shfl_xor(s1, 32);
    s2 += __shfl_xor(s2, 16); s2 += __shfl_xor(s2, 32);
    float mean = s1 * (1.f / 128.f);
    float rstd = rsqrtf(fmaf(-mean, mean, s2 * (1.f / 128.f)) + EPS);
    float ms = -mean * rstd;
    const f32x2 rs = {rstd, rstd}, msv = {ms, ms};

#pragma unroll
    for (int f = 0; f < 8; ++f) {
      float4 gv = *(const float4*)(g3 + 16 * f + 4 * q);
      float4 bv = *(const float4*)(b3 + 16 * f + 4 * q);
      float4 R = *(const float4*)(xr + 16 * f + 4 * q);
      f32x2 a01 = __builtin_shufflevector(acc[f], acc[f], 0, 1);
      f32x2 a23 = __builtin_shufflevector(acc[f], acc[f], 2, 3);
      f32x2 o01 = mish2(ln2(a01, rs, msv, (f32x2){gv.x, gv.y}, (f32x2){bv.x, bv.y}))
                  + (f32x2){R.x, R.y};
      f32x2 o23 = mish2(ln2(a23, rs, msv, (f32x2){gv.z, gv.w}, (f32x2){bv.z, bv.w}))
                  + (f32x2){R.z, R.w};
      float4 ov = {o01[0], o01[1], o23[0], o23[1]};
      *(float4*)&x19c[(size_t)cell * 128 + 16 * f + 4 * q] = ov;
    }
  }
}

// ---------------------------------------------------------------------------
// Expand v2: transposed tile, float4 write phase.
// ---------------------------------------------------------------------------
__global__ __launch_bounds__(256) void expand_kernel(
    const float* __restrict__ x19c, const int* __restrict__ invmap,
    float* __restrict__ out)
{
  __shared__ float tile[128][68];   // 34816 B
  const int tid   = threadIdx.x;
  const int pbase = blockIdx.x * 64;
  const int r     = tid & 63;      // pos within tile
  const int part  = tid >> 6;      // quarter of the 128-ch row
  const int cell  = invmap[pbase + r];
  if (cell >= 0) {
    const float* src = x19c + (size_t)cell * 128 + part * 32;
#pragma unroll
    for (int k = 0; k < 8; ++k) {
      float4 v = *(const float4*)(src + 4 * k);
      tile[part * 32 + 4 * k + 0][r] = v.x;
      tile[part * 32 + 4 * k + 1][r] = v.y;
      tile[part * 32 + 4 * k + 2][r] = v.z;
      tile[part * 32 + 4 * k + 3][r] = v.w;
    }
  } else {
#pragma unroll
    for (int k = 0; k < 32; ++k) tile[part * 32 + k][r] = 0.f;
  }
  __syncthreads();
  // write phase: 2048 float4 units / 256 threads = 8 iterations
#pragma unroll
  for (int k = 0; k < 8; ++k) {
    int unit = k * 256 + tid;        // 0..2047
    int c    = unit >> 4;            // 0..127
    int quad = unit & 15;            // 0..15
    float4 v = *(const float4*)&tile[c][quad * 4];
    *(float4*)&out[(size_t)c * HW + pbase + quad * 4] = v;
  }
}

// ---------------------------------------------------------------------------
extern "C" void kernel_launch(void* const* d_in, const int* in_sizes, int n_in,
                              void* d_out, int out_size, void* d_ws, size_t ws_size,
                              hipStream_t stream) {
  const float* voxels   = (const float*)d_in[0];
  const float* vmask    = (const float*)d_in[1];
  const int*   bevsidx  = (const int*)d_in[2];
  const int*   bevcoors = (const int*)d_in[3];
  const float* bevmask  = (const float*)d_in[4];
  const float* vfe1_W = (const float*)d_in[5];
  const float* vfe1_g = (const float*)d_in[6];
  const float* vfe1_b = (const float*)d_in[7];
  const float* vfe2_W = (const float*)d_in[8];
  const float* vfe2_g = (const float*)d_in[9];
  const float* vfe2_b = (const float*)d_in[10];
  const float* vfe3_W = (const float*)d_in[11];
  const float* vfe3_g = (const float*)d_in[12];
  const float* vfe3_b = (const float*)d_in[13];
  const float* vfe4_W = (const float*)d_in[14];
  const float* vfe4_g = (const float*)d_in[15];
  const float* vfe4_b = (const float*)d_in[16];
  const float* bfe1_W  = (const float*)d_in[17];
  const float* bfe1_g  = (const float*)d_in[18];
  const float* bfe1_b  = (const float*)d_in[19];
  const float* bfe2a_W = (const float*)d_in[20];
  const float* bfe2a_g = (const float*)d_in[21];
  const float* bfe2a_b = (const float*)d_in[22];
  const float* bfe2b_W = (const float*)d_in[23];
  const float* bfe2b_g = (const float*)d_in[24];
  const float* bfe2b_b = (const float*)d_in[25];
  const float* bfe3_W  = (const float*)d_in[26];
  const float* bfe3_g  = (const float*)d_in[27];
  const float* bfe3_b  = (const float*)d_in[28];

  unsigned short* voxelwise = (unsigned short*)d_ws;      // NV*64 bf16
  float* x17buf = (float*)(voxelwise + (size_t)NV * 64);  // NB*128 floats
  float* x19c   = x17buf + (size_t)NB * 128;              // NB*128 floats
  int*   invmap = (int*)(x19c + (size_t)NB * 128);        // HW ints
  short* wbase  = (short*)(invmap + HW);
  short* w1h  = wbase;                                // 65536
  short* w2ah = w1h + 65536;                          // 16384
  short* w2bh = w2ah + 16384;                         // 8192
  short* w3h  = w2bh + 8192;                          // 16384
  short* w3l  = w3h + 16384;                          // 16384
  float* out = (float*)d_out;

  // clear only the 857 KB inverse map (out is fully written by expand_kernel)
  hipMemsetAsync(invmap, 0xFF, (size_t)HW * sizeof(int), stream);

  // fused vfe + weight-pack
  vfe_pack_kernel<<<VFE_BLOCKS + PACK_BLOCKS, 512, 0, stream>>>(
      voxels, vmask,
      vfe1_W, vfe1_g, vfe1_b, vfe2_W, vfe2_g, vfe2_b,
      vfe3_W, vfe3_g, vfe3_b, vfe4_W, vfe4_g, vfe4_b,
      voxelwise,
      bfe1_W, bfe2a_W, bfe2b_W, bfe3_W, bevcoors,
      w1h, w2ah, w2bh, w3h, w3l, invmap);

  bfe12_mfma10_kernel<<<NB / 4, 512, 0, stream>>>(
      voxelwise, bevsidx, bevmask,
      w1h, bfe1_g, bfe1_b,
      w2ah, bfe2a_g, bfe2a_b,
      w2bh, bfe2b_g, bfe2b_b,
      x17buf);

  bfe3_mfma5_kernel<<<NB / 16, 64, 0, stream>>>(
      x17buf, w3h, w3l, bfe3_g, bfe3_b, x19c);

  expand_kernel<<<HW / 64, 256, 0, stream>>>(x19c, invmap, out);
}